// Round 7
// baseline (813.028 us; speedup 1.0000x reference)
//
#include <hip/hip_runtime.h>

#define N_NODES 100000
#define NPAD 100096   // 391 * 256
#define NBLK 391      // dst buckets of 256 nodes / row blocks

using bf16x8 = __attribute__((ext_vector_type(8))) short;
using f32x4  = __attribute__((ext_vector_type(4))) float;

__device__ inline short f2bf(float f) {               // RNE f32 -> bf16
    unsigned int u = __float_as_uint(f);
    unsigned int r = (u + 0x7FFFu + ((u >> 16) & 1u)) >> 16;
    return (short)r;
}
__device__ inline float bf2f_lo(unsigned int w) { return __uint_as_float(w << 16); }
__device__ inline float bf2f_hi(unsigned int w) { return __uint_as_float(w & 0xFFFF0000u); }

// map linear bid -> (rowBlk, colHalf) such that both colHalves of a row block
// land on the SAME XCD (round-robin assumption; perf-only heuristic).
__device__ inline bool xcd_map(int bid, int& row, int& col) {
    const int RP = (NBLK + 7) / 8;           // 49 row-blocks per XCD
    const int xcd = bid & 7;
    const int i = bid >> 3;
    row = xcd * RP + (i >> 1);
    col = i & 1;
    return row < NBLK;
}
#define GEMM_GRID (8 * 2 * ((NBLK + 7) / 8))   // 784

// ---------------- pass 0: bucket histogram (LDS pre-reduce) ----------------
__global__ __launch_bounds__(256)
void cbuck_kernel(const int* __restrict__ dst, int* __restrict__ bucket_cnt, int E) {
    __shared__ int cnt[NBLK];
    const int tid = threadIdx.x;
    for (int i = tid; i < NBLK; i += 256) cnt[i] = 0;
    __syncthreads();
    const int e0 = blockIdx.x * 4096;
    #pragma unroll
    for (int k = 0; k < 16; ++k) {
        int e = e0 + k * 256 + tid;
        if (e < E) atomicAdd(&cnt[dst[e] >> 8], 1);
    }
    __syncthreads();
    for (int i = tid; i < NBLK; i += 256)
        if (cnt[i]) atomicAdd(&bucket_cnt[i], cnt[i]);
}

// ---------------- pass 1: scan of 391 bucket counts ----------------
__global__ void scan391_kernel(const int* __restrict__ bucket_cnt, int* __restrict__ bucket_base,
                               int* __restrict__ bucket_cursor, int* __restrict__ offsets) {
    __shared__ int s[512];
    int t = threadIdx.x;
    int v = (t < NBLK) ? bucket_cnt[t] : 0;
    s[t] = v;
    __syncthreads();
    #pragma unroll
    for (int off = 1; off < 512; off <<= 1) {
        int u = (t >= off) ? s[t - off] : 0;
        __syncthreads();
        s[t] += u;
        __syncthreads();
    }
    if (t < NBLK) {
        int excl = s[t] - v;
        bucket_base[t] = excl;
        bucket_cursor[t] = excl;
    }
    if (t == NBLK - 1) {
        bucket_base[NBLK] = s[t];
        offsets[N_NODES] = s[t];      // = E
    }
}

// ---------------- pass 2: bin edges by dst>>8, dense packed writes ----------------
__global__ __launch_bounds__(256)
void bin_kernel(const int* __restrict__ src, const int* __restrict__ dst,
                int* __restrict__ bucket_cursor, unsigned int* __restrict__ bin, int E) {
    __shared__ int cnt[NBLK];
    __shared__ int base_l[NBLK];
    const int tid = threadIdx.x;
    const int e0 = blockIdx.x * 4096;
    for (int i = tid; i < NBLK; i += 256) cnt[i] = 0;
    __syncthreads();
    int myb[16]; unsigned myv[16];
    #pragma unroll
    for (int k = 0; k < 16; ++k) {
        int e = e0 + k * 256 + tid;
        if (e < E) {
            int d = dst[e];
            myb[k] = d >> 8;
            myv[k] = (unsigned)src[e] | ((unsigned)(d & 255) << 20);
            atomicAdd(&cnt[myb[k]], 1);
        } else myb[k] = -1;
    }
    __syncthreads();
    for (int i = tid; i < NBLK; i += 256) {
        int c = cnt[i];
        base_l[i] = c ? atomicAdd(&bucket_cursor[i], c) : 0;
        cnt[i] = 0;
    }
    __syncthreads();
    #pragma unroll
    for (int k = 0; k < 16; ++k) {
        if (myb[k] >= 0) {
            int slot = base_l[myb[k]] + atomicAdd(&cnt[myb[k]], 1);
            bin[slot] = myv[k];
        }
    }
}

// ---------------- pass 3: per-bucket place; also emits per-node offsets ----------------
__global__ __launch_bounds__(256)
void place_kernel(const unsigned int* __restrict__ bin, const int* __restrict__ bucket_base,
                  int* __restrict__ offsets, int* __restrict__ sorted) {
    __shared__ int cnt[256];
    __shared__ int cur[256];
    __shared__ int wsum[4];
    const int b = blockIdx.x, tid = threadIdx.x;
    const int lane = tid & 63, wave = tid >> 6;
    const int s = bucket_base[b];
    const int e = bucket_base[b + 1];
    cnt[tid] = 0;
    __syncthreads();
    for (int i = s + tid; i < e; i += 256) atomicAdd(&cnt[bin[i] >> 20], 1);
    __syncthreads();
    int v = cnt[tid];
    int x = v;
    #pragma unroll
    for (int off = 1; off < 64; off <<= 1) {
        int t = __shfl_up(x, off, 64);
        if (lane >= off) x += t;
    }
    if (lane == 63) wsum[wave] = x;
    __syncthreads();
    int woff = 0;
    #pragma unroll
    for (int w = 0; w < 4; ++w) if (w < wave) woff += wsum[w];
    int excl = s + woff + x - v;
    cur[tid] = excl;
    int node = b * 256 + tid;
    if (node < N_NODES) offsets[node] = excl;
    __syncthreads();
    for (int i = s + tid; i < e; i += 256) {
        unsigned w = bin[i];
        int p = atomicAdd(&cur[w >> 20], 1);
        sorted[p] = (int)(w & 0xFFFFFu);
    }
}

// ---------------- fused prep: cast x (slice-major + packed) AND pack all 4 weights ----------------
__global__ __launch_bounds__(256)
void prep_kernel(const float* __restrict__ x, short* __restrict__ xslice, short* __restrict__ xpack,
                 const float* __restrict__ Wl1, const float* __restrict__ Wr1,
                 const float* __restrict__ Wl2, const float* __restrict__ Wr2,
                 short* __restrict__ wl1p, short* __restrict__ wr1p,
                 short* __restrict__ wl2p, short* __restrict__ wr2p) {
    int t = blockIdx.x * 256 + threadIdx.x;
    if (t < N_NODES * 16) {
        int row = t >> 4;
        int kc = (t & 15) << 3;
        const float4 v0 = *(const float4*)(x + (size_t)row * 128 + kc);
        const float4 v1 = *(const float4*)(x + (size_t)row * 128 + kc + 4);
        __align__(16) short s[8] = {f2bf(v0.x), f2bf(v0.y), f2bf(v0.z), f2bf(v0.w),
                                    f2bf(v1.x), f2bf(v1.y), f2bf(v1.z), f2bf(v1.w)};
        size_t sidx = ((size_t)(kc >> 4) * NPAD + row) * 16 + (kc & 8);
        *(int4*)(xslice + sidx) = *(const int4*)s;
        size_t pidx = ((size_t)(row >> 4) * 16 + (kc >> 3)) * 128 + (size_t)(row & 15) * 8;
        *(int4*)(xpack + pidx) = *(const int4*)s;
        return;
    }
    int u = t - N_NODES * 16;
    if (u >= 4 * 32768) return;
    const int w = u >> 15;        // which weight
    const int t2 = u & 32767;
    const float* W; short* P; int K, NC;
    if (w == 0)      { W = Wl1; P = wl1p; K = 128; NC = 256; }
    else if (w == 1) { W = Wr1; P = wr1p; K = 128; NC = 256; }
    else if (w == 2) { W = Wl2; P = wl2p; K = 256; NC = 128; }
    else             { W = Wr2; P = wr2p; K = 256; NC = 128; }
    int k = t2 / NC, c = t2 % NC;
    P[((size_t)(c >> 4) * (K >> 3) + (k >> 3)) * 128 + (size_t)(c & 15) * 8 + (k & 7)] = f2bf(W[t2]);
}

// ---------------- XCD-pinned slice-gather mean aggregation ----------------
// tab is [8][NPAD][16] bf16 slice-major. Block handles slice = bid&7 (lands on
// XCD bid%8 under round-robin dispatch -> 3.2MB slice table stays L2-resident),
// nodes [(bid>>3)*32, +32): 8 waves x 4 nodes. Per node: 2-lane groups, 32
// edges in flight per wave. MODE 0: packed bf16 chunk out. MODE 1: f32 RMW.
template<int MODE>
__global__ __launch_bounds__(512)
void aggslice_kernel(const short* __restrict__ tab0, const int* __restrict__ offsets,
                     const int* __restrict__ srcs,
                     short* __restrict__ outpack, float* __restrict__ outf) {
    const int slice = blockIdx.x & 7;
    const int nbase = (blockIdx.x >> 3) * 32;
    const int wave = threadIdx.x >> 6, lane = threadIdx.x & 63;
    const int g = lane >> 1;            // edge group 0..31
    const int k = lane & 1;             // 8-dim half
    const short* tab = tab0 + (size_t)slice * NPAD * 16;
    #pragma unroll
    for (int t = 0; t < 4; ++t) {
        const int node = nbase + wave * 4 + t;
        if (node >= N_NODES) return;    // wave-uniform
        const int s = offsets[node], e = offsets[node + 1];
        const float inv = 1.0f / (float)max(e - s, 1);
        float acc[8] = {0.f, 0.f, 0.f, 0.f, 0.f, 0.f, 0.f, 0.f};
        for (int j = s + g; j < e; j += 32) {
            const int idx = srcs[j];
            const uint4 w = *(const uint4*)(tab + (size_t)idx * 16 + k * 8);
            acc[0] += bf2f_lo(w.x); acc[1] += bf2f_hi(w.x);
            acc[2] += bf2f_lo(w.y); acc[3] += bf2f_hi(w.y);
            acc[4] += bf2f_lo(w.z); acc[5] += bf2f_hi(w.z);
            acc[6] += bf2f_lo(w.w); acc[7] += bf2f_hi(w.w);
        }
        #pragma unroll
        for (int off = 2; off <= 32; off <<= 1)
            #pragma unroll
            for (int q = 0; q < 8; ++q) acc[q] += __shfl_xor(acc[q], off, 64);
        if (g == 0) {
            if (MODE == 0) {
                __align__(16) short r[8];
                #pragma unroll
                for (int q = 0; q < 8; ++q) r[q] = f2bf(acc[q] * inv);
                size_t pidx = ((size_t)(node >> 4) * 16 + 2 * slice + k) * 128
                            + (size_t)(node & 15) * 8;
                *(int4*)(outpack + pidx) = *(const int4*)r;
            } else {
                float* o = outf + (size_t)node * 128 + slice * 16 + k * 8;
                float4 q0 = *(const float4*)o;
                float4 q1 = *(const float4*)(o + 4);
                q0.x += acc[0] * inv; q0.y += acc[1] * inv;
                q0.z += acc[2] * inv; q0.w += acc[3] * inv;
                q1.x += acc[4] * inv; q1.y += acc[5] * inv;
                q1.z += acc[6] * inv; q1.w += acc[7] * inv;
                *(float4*)o = q0;
                *(float4*)(o + 4) = q1;
            }
        }
    }
}

// ---------------- layer-1 GEMM: h = relu(A0@B0 + A1@B1 + bias), packed bf16 out ----------------
// wave tile 64 rows x 128 cols; linear grid with XCD-pair swizzle (rowBlk, colHalf).
__global__ __launch_bounds__(256)
void gemm1_kernel(const short* __restrict__ A0, const short* __restrict__ A1,
                  const short* __restrict__ B0, const short* __restrict__ B1,
                  const float* __restrict__ bias, short* __restrict__ opack) {
    constexpr int KB = 16, KS = 4, S = 8;   // k-chunks/row, steps/phase, total steps
    __shared__ float sC[4][32][132];
    int rowBlk, colHalf;
    if (!xcd_map(blockIdx.x, rowBlk, colHalf)) return;
    const int tid = threadIdx.x, wave = tid >> 6, lane = tid & 63;
    const int lhi = lane >> 4, llo = lane & 15;
    const int rowBase = rowBlk * 256 + wave * 64;
    const int colBase = colHalf * 128;
    const int rowTile = rowBase >> 4, colTile = colBase >> 4;

    f32x4 acc[4][8];
    #pragma unroll
    for (int i = 0; i < 4; ++i)
        #pragma unroll
        for (int j = 0; j < 8; ++j)
            #pragma unroll
            for (int r = 0; r < 4; ++r) acc[i][j][r] = 0.f;

    bf16x8 a[4];
    #pragma unroll
    for (int i = 0; i < 4; ++i)
        a[i] = *(const bf16x8*)(A0 + ((size_t)(rowTile + i) * KB + lhi) * 128 + (size_t)llo * 8);

    #pragma unroll
    for (int s = 0; s < S; ++s) {
        const short* B = (s >= KS) ? B1 : B0;
        const int kb = (s - (s >= KS ? KS : 0)) * 4 + lhi;
        bf16x8 b[8];
        #pragma unroll
        for (int j = 0; j < 8; ++j)
            b[j] = *(const bf16x8*)(B + ((size_t)(colTile + j) * KB + kb) * 128 + (size_t)llo * 8);
        bf16x8 an[4];
        if (s + 1 < S) {
            const int s1 = s + 1;
            const short* A = (s1 >= KS) ? A1 : A0;
            const int kb1 = (s1 - (s1 >= KS ? KS : 0)) * 4 + lhi;
            #pragma unroll
            for (int i = 0; i < 4; ++i)
                an[i] = *(const bf16x8*)(A + ((size_t)(rowTile + i) * KB + kb1) * 128 + (size_t)llo * 8);
        }
        #pragma unroll
        for (int i = 0; i < 4; ++i)
            #pragma unroll
            for (int j = 0; j < 8; ++j)
                acc[i][j] = __builtin_amdgcn_mfma_f32_16x16x32_bf16(a[i], b[j], acc[i][j], 0, 0, 0);
        if (s + 1 < S) {
            #pragma unroll
            for (int i = 0; i < 4; ++i) a[i] = an[i];
        }
    }

    #pragma unroll
    for (int j = 0; j < 8; ++j) {
        float bv = bias[colBase + j * 16 + llo];
        #pragma unroll
        for (int i = 0; i < 4; ++i)
            #pragma unroll
            for (int r = 0; r < 4; ++r)
                acc[i][j][r] = fmaxf(acc[i][j][r] + bv, 0.f);
    }

    #pragma unroll
    for (int half = 0; half < 2; ++half) {
        #pragma unroll
        for (int i2 = 0; i2 < 2; ++i2) {
            const int i = half * 2 + i2;
            #pragma unroll
            for (int j = 0; j < 8; ++j)
                #pragma unroll
                for (int r = 0; r < 4; ++r)
                    sC[wave][i2 * 16 + lhi * 4 + r][j * 16 + llo] = acc[i][j][r];
        }
        #pragma unroll
        for (int it = 0; it < 8; ++it) {
            const int r = it * 4 + (lane >> 4);
            const int c = (lane & 15) * 8;
            const int grow = rowBase + half * 32 + r;
            if (grow < N_NODES) {
                float4 v0 = *(const float4*)&sC[wave][r][c];
                float4 v1 = *(const float4*)&sC[wave][r][c + 4];
                __align__(16) short sv[8] = {f2bf(v0.x), f2bf(v0.y), f2bf(v0.z), f2bf(v0.w),
                                             f2bf(v1.x), f2bf(v1.y), f2bf(v1.z), f2bf(v1.w)};
                size_t pidx = ((size_t)(grow >> 4) * 32 + ((colBase + c) >> 3)) * 128
                            + (size_t)(grow & 15) * 8;
                *(int4*)(opack + pidx) = *(const int4*)sv;
            }
        }
    }
}

// ---------------- layer-2 dual-output GEMM: p = A@B0 (slice-major bf16); q = A@B1 + bias (f32) ----------------
// wave tile 64 rows x 64 cols of BOTH outputs; linear grid with XCD-pair swizzle.
__global__ __launch_bounds__(256)
void gemm2_kernel(const short* __restrict__ A, const short* __restrict__ B0,
                  const short* __restrict__ B1, const float* __restrict__ bias,
                  short* __restrict__ pslice, float* __restrict__ qf32) {
    constexpr int KB = 32, S = 8;
    __shared__ float sC[4][32][68];
    int rowBlk, colHalf;
    if (!xcd_map(blockIdx.x, rowBlk, colHalf)) return;
    const int tid = threadIdx.x, wave = tid >> 6, lane = tid & 63;
    const int lhi = lane >> 4, llo = lane & 15;
    const int rowBase = rowBlk * 256 + wave * 64;
    const int colBase = colHalf * 64;
    const int rowTile = rowBase >> 4, colTile = colBase >> 4;

    f32x4 accp[4][4], accq[4][4];
    #pragma unroll
    for (int i = 0; i < 4; ++i)
        #pragma unroll
        for (int j = 0; j < 4; ++j)
            #pragma unroll
            for (int r = 0; r < 4; ++r) { accp[i][j][r] = 0.f; accq[i][j][r] = 0.f; }

    bf16x8 a[4];
    #pragma unroll
    for (int i = 0; i < 4; ++i)
        a[i] = *(const bf16x8*)(A + ((size_t)(rowTile + i) * KB + lhi) * 128 + (size_t)llo * 8);

    #pragma unroll
    for (int s = 0; s < S; ++s) {
        const int kb = s * 4 + lhi;
        bf16x8 b0[4], b1[4];
        #pragma unroll
        for (int j = 0; j < 4; ++j) {
            b0[j] = *(const bf16x8*)(B0 + ((size_t)(colTile + j) * KB + kb) * 128 + (size_t)llo * 8);
            b1[j] = *(const bf16x8*)(B1 + ((size_t)(colTile + j) * KB + kb) * 128 + (size_t)llo * 8);
        }
        bf16x8 an[4];
        if (s + 1 < S) {
            const int kb1 = (s + 1) * 4 + lhi;
            #pragma unroll
            for (int i = 0; i < 4; ++i)
                an[i] = *(const bf16x8*)(A + ((size_t)(rowTile + i) * KB + kb1) * 128 + (size_t)llo * 8);
        }
        #pragma unroll
        for (int i = 0; i < 4; ++i)
            #pragma unroll
            for (int j = 0; j < 4; ++j) {
                accp[i][j] = __builtin_amdgcn_mfma_f32_16x16x32_bf16(a[i], b0[j], accp[i][j], 0, 0, 0);
                accq[i][j] = __builtin_amdgcn_mfma_f32_16x16x32_bf16(a[i], b1[j], accq[i][j], 0, 0, 0);
            }
        if (s + 1 < S) {
            #pragma unroll
            for (int i = 0; i < 4; ++i) a[i] = an[i];
        }
    }

    // p epilogue: bf16 slice-major [8][NPAD][16]
    #pragma unroll
    for (int half = 0; half < 2; ++half) {
        #pragma unroll
        for (int i2 = 0; i2 < 2; ++i2) {
            const int i = half * 2 + i2;
            #pragma unroll
            for (int j = 0; j < 4; ++j)
                #pragma unroll
                for (int r = 0; r < 4; ++r)
                    sC[wave][i2 * 16 + lhi * 4 + r][j * 16 + llo] = accp[i][j][r];
        }
        #pragma unroll
        for (int it = 0; it < 4; ++it) {
            const int r = it * 8 + (lane >> 3);
            const int c = (lane & 7) * 8;
            const int grow = rowBase + half * 32 + r;
            if (grow < N_NODES) {
                float4 v0 = *(const float4*)&sC[wave][r][c];
                float4 v1 = *(const float4*)&sC[wave][r][c + 4];
                __align__(16) short sv[8] = {f2bf(v0.x), f2bf(v0.y), f2bf(v0.z), f2bf(v0.w),
                                             f2bf(v1.x), f2bf(v1.y), f2bf(v1.z), f2bf(v1.w)};
                const int cc = colBase + c;
                size_t sidx = ((size_t)(cc >> 4) * NPAD + grow) * 16 + (cc & 8);
                *(int4*)(pslice + sidx) = *(const int4*)sv;
            }
        }
    }

    // q epilogue: f32 + bias
    #pragma unroll
    for (int j = 0; j < 4; ++j) {
        float bv = bias[colBase + j * 16 + llo];
        #pragma unroll
        for (int i = 0; i < 4; ++i)
            #pragma unroll
            for (int r = 0; r < 4; ++r) accq[i][j][r] += bv;
    }
    #pragma unroll
    for (int half = 0; half < 2; ++half) {
        #pragma unroll
        for (int i2 = 0; i2 < 2; ++i2) {
            const int i = half * 2 + i2;
            #pragma unroll
            for (int j = 0; j < 4; ++j)
                #pragma unroll
                for (int r = 0; r < 4; ++r)
                    sC[wave][i2 * 16 + lhi * 4 + r][j * 16 + llo] = accq[i][j][r];
        }
        #pragma unroll
        for (int it = 0; it < 4; ++it) {
            const int r = it * 8 + (lane >> 3);
            const int c = (lane & 7) * 8;
            const int grow = rowBase + half * 32 + r;
            if (grow < N_NODES) {
                float4 v0 = *(const float4*)&sC[wave][r][c];
                float4 v1 = *(const float4*)&sC[wave][r][c + 4];
                *(float4*)(qf32 + (size_t)grow * 128 + colBase + c) = v0;
                *(float4*)(qf32 + (size_t)grow * 128 + colBase + c + 4) = v1;
            }
        }
    }
}

extern "C" void kernel_launch(void* const* d_in, const int* in_sizes, int n_in,
                              void* d_out, int out_size, void* d_ws, size_t ws_size,
                              hipStream_t stream) {
    const float* x   = (const float*)d_in[0];
    const int*   ei  = (const int*)d_in[1];
    const float* Wl1 = (const float*)d_in[2];
    const float* b1  = (const float*)d_in[3];
    const float* Wr1 = (const float*)d_in[4];
    const float* Wl2 = (const float*)d_in[5];
    const float* b2  = (const float*)d_in[6];
    const float* Wr2 = (const float*)d_in[7];
    const int E = in_sizes[1] / 2;
    const int* src = ei;
    const int* dst = ei + E;

    // workspace layout
    short* h_pack  = (short*)d_ws;                   // NPAD*256
    short* agg1p   = h_pack  + (size_t)NPAD * 256;   // NPAD*128
    short* x_slice = agg1p   + (size_t)NPAD * 128;   // NPAD*128 ([8][NPAD][16])
    short* x_pack  = x_slice + (size_t)NPAD * 128;   // NPAD*128
    short* p_slice = x_pack  + (size_t)NPAD * 128;   // NPAD*128 ([8][NPAD][16])
    short* wl1p    = p_slice + (size_t)NPAD * 128;   // 32768
    short* wr1p    = wl1p + 32768;
    short* wl2p    = wr1p + 32768;
    short* wr2p    = wl2p + 32768;
    int* bucket_cnt    = (int*)(wr2p + 32768);      // NBLK+1
    int* bucket_base   = bucket_cnt + NBLK + 1;     // NBLK+1
    int* bucket_cursor = bucket_base + NBLK + 1;    // NBLK+1
    int* offsets       = bucket_cursor + NBLK + 1;  // N+1
    unsigned int* bin  = (unsigned int*)(offsets + N_NODES + 1); // E
    int* sorted        = (int*)(bin + E);           // E

    const int nbin = (E + 4095) / 4096;
    const int agg_grid = 8 * ((N_NODES + 31) / 32); // 25000

    // CSR build (binned two-pass counting sort)
    hipMemsetAsync(bucket_cnt, 0, (NBLK + 1) * sizeof(int), stream);
    cbuck_kernel<<<nbin, 256, 0, stream>>>(dst, bucket_cnt, E);
    scan391_kernel<<<1, 512, 0, stream>>>(bucket_cnt, bucket_base, bucket_cursor, offsets);
    bin_kernel<<<nbin, 256, 0, stream>>>(src, dst, bucket_cursor, bin, E);
    place_kernel<<<NBLK, 256, 0, stream>>>(bin, bucket_base, offsets, sorted);

    // fused bf16 conversions / packing (x + all 4 weights)
    prep_kernel<<<(N_NODES * 16 + 4 * 32768 + 255) / 256, 256, 0, stream>>>(
        x, x_slice, x_pack, Wl1, Wr1, Wl2, Wr2, wl1p, wr1p, wl2p, wr2p);

    // layer 1: agg(x) -> h = relu([mean,x]@[Wl1;Wr1] + b1) (packed)
    aggslice_kernel<0><<<agg_grid, 512, 0, stream>>>(x_slice, offsets, sorted, agg1p, nullptr);
    gemm1_kernel<<<GEMM_GRID, 256, 0, stream>>>(agg1p, x_pack, wl1p, wr1p, b1, h_pack);

    // layer 2 (commuted): p = h@Wl2 (slice-major); q = h@Wr2 + b2 -> d_out; d_out += mean(p)
    gemm2_kernel<<<GEMM_GRID, 256, 0, stream>>>(h_pack, wl2p, wr2p, b2, p_slice, (float*)d_out);
    aggslice_kernel<1><<<agg_grid, 512, 0, stream>>>(p_slice, offsets, sorted, nullptr, (float*)d_out);
}

// Round 8
// 294.665 us; speedup vs baseline: 2.7592x; 2.7592x over previous
//
#include <hip/hip_runtime.h>

#define N_NODES 100000
#define NPAD 100096   // 391 * 256
#define NBLK 391      // dst buckets of 256 nodes / row blocks

using bf16x8 = __attribute__((ext_vector_type(8))) short;
using f32x4  = __attribute__((ext_vector_type(4))) float;

__device__ inline short f2bf(float f) {               // RNE f32 -> bf16
    unsigned int u = __float_as_uint(f);
    unsigned int r = (u + 0x7FFFu + ((u >> 16) & 1u)) >> 16;
    return (short)r;
}
__device__ inline float bf2f_lo(unsigned int w) { return __uint_as_float(w << 16); }
__device__ inline float bf2f_hi(unsigned int w) { return __uint_as_float(w & 0xFFFF0000u); }

// map linear bid -> (rowBlk, colHalf) such that both colHalves of a row block
// land on the SAME XCD (round-robin assumption; perf-only heuristic).
__device__ inline bool xcd_map(int bid, int& row, int& col) {
    const int RP = (NBLK + 7) / 8;           // 49 row-blocks per XCD
    const int xcd = bid & 7;
    const int i = bid >> 3;
    row = xcd * RP + (i >> 1);
    col = i & 1;
    return row < NBLK;
}
#define GEMM_GRID (8 * 2 * ((NBLK + 7) / 8))   // 784

// ---------------- pass 0: bucket histogram (LDS pre-reduce) ----------------
__global__ __launch_bounds__(256)
void cbuck_kernel(const int* __restrict__ dst, int* __restrict__ bucket_cnt, int E) {
    __shared__ int cnt[NBLK];
    const int tid = threadIdx.x;
    for (int i = tid; i < NBLK; i += 256) cnt[i] = 0;
    __syncthreads();
    const int e0 = blockIdx.x * 4096;
    #pragma unroll
    for (int k = 0; k < 16; ++k) {
        int e = e0 + k * 256 + tid;
        if (e < E) atomicAdd(&cnt[dst[e] >> 8], 1);
    }
    __syncthreads();
    for (int i = tid; i < NBLK; i += 256)
        if (cnt[i]) atomicAdd(&bucket_cnt[i], cnt[i]);
}

// ---------------- pass 1: scan of 391 bucket counts ----------------
__global__ void scan391_kernel(const int* __restrict__ bucket_cnt, int* __restrict__ bucket_base,
                               int* __restrict__ bucket_cursor, int* __restrict__ offsets) {
    __shared__ int s[512];
    int t = threadIdx.x;
    int v = (t < NBLK) ? bucket_cnt[t] : 0;
    s[t] = v;
    __syncthreads();
    #pragma unroll
    for (int off = 1; off < 512; off <<= 1) {
        int u = (t >= off) ? s[t - off] : 0;
        __syncthreads();
        s[t] += u;
        __syncthreads();
    }
    if (t < NBLK) {
        int excl = s[t] - v;
        bucket_base[t] = excl;
        bucket_cursor[t] = excl;
    }
    if (t == NBLK - 1) {
        bucket_base[NBLK] = s[t];
        offsets[N_NODES] = s[t];      // = E
    }
}

// ---------------- pass 2: bin edges by dst>>8, dense packed writes ----------------
__global__ __launch_bounds__(256)
void bin_kernel(const int* __restrict__ src, const int* __restrict__ dst,
                int* __restrict__ bucket_cursor, unsigned int* __restrict__ bin, int E) {
    __shared__ int cnt[NBLK];
    __shared__ int base_l[NBLK];
    const int tid = threadIdx.x;
    const int e0 = blockIdx.x * 4096;
    for (int i = tid; i < NBLK; i += 256) cnt[i] = 0;
    __syncthreads();
    int myb[16]; unsigned myv[16];
    #pragma unroll
    for (int k = 0; k < 16; ++k) {
        int e = e0 + k * 256 + tid;
        if (e < E) {
            int d = dst[e];
            myb[k] = d >> 8;
            myv[k] = (unsigned)src[e] | ((unsigned)(d & 255) << 20);
            atomicAdd(&cnt[myb[k]], 1);
        } else myb[k] = -1;
    }
    __syncthreads();
    for (int i = tid; i < NBLK; i += 256) {
        int c = cnt[i];
        base_l[i] = c ? atomicAdd(&bucket_cursor[i], c) : 0;
        cnt[i] = 0;
    }
    __syncthreads();
    #pragma unroll
    for (int k = 0; k < 16; ++k) {
        if (myb[k] >= 0) {
            int slot = base_l[myb[k]] + atomicAdd(&cnt[myb[k]], 1);
            bin[slot] = myv[k];
        }
    }
}

// ---------------- pass 3: per-bucket place; also emits per-node offsets ----------------
__global__ __launch_bounds__(256)
void place_kernel(const unsigned int* __restrict__ bin, const int* __restrict__ bucket_base,
                  int* __restrict__ offsets, int* __restrict__ sorted) {
    __shared__ int cnt[256];
    __shared__ int cur[256];
    __shared__ int wsum[4];
    const int b = blockIdx.x, tid = threadIdx.x;
    const int lane = tid & 63, wave = tid >> 6;
    const int s = bucket_base[b];
    const int e = bucket_base[b + 1];
    cnt[tid] = 0;
    __syncthreads();
    for (int i = s + tid; i < e; i += 256) atomicAdd(&cnt[bin[i] >> 20], 1);
    __syncthreads();
    int v = cnt[tid];
    int x = v;
    #pragma unroll
    for (int off = 1; off < 64; off <<= 1) {
        int t = __shfl_up(x, off, 64);
        if (lane >= off) x += t;
    }
    if (lane == 63) wsum[wave] = x;
    __syncthreads();
    int woff = 0;
    #pragma unroll
    for (int w = 0; w < 4; ++w) if (w < wave) woff += wsum[w];
    int excl = s + woff + x - v;
    cur[tid] = excl;
    int node = b * 256 + tid;
    if (node < N_NODES) offsets[node] = excl;
    __syncthreads();
    for (int i = s + tid; i < e; i += 256) {
        unsigned w = bin[i];
        int p = atomicAdd(&cur[w >> 20], 1);
        sorted[p] = (int)(w & 0xFFFFFu);
    }
}

// ---------------- fused prep: cast x (row + packed) AND pack all 4 weights ----------------
__global__ __launch_bounds__(256)
void prep_kernel(const float* __restrict__ x, short* __restrict__ xrow, short* __restrict__ xpack,
                 const float* __restrict__ Wl1, const float* __restrict__ Wr1,
                 const float* __restrict__ Wl2, const float* __restrict__ Wr2,
                 short* __restrict__ wl1p, short* __restrict__ wr1p,
                 short* __restrict__ wl2p, short* __restrict__ wr2p) {
    int t = blockIdx.x * 256 + threadIdx.x;
    if (t < N_NODES * 16) {
        int row = t >> 4;
        int kc = (t & 15) << 3;
        const float4 v0 = *(const float4*)(x + (size_t)row * 128 + kc);
        const float4 v1 = *(const float4*)(x + (size_t)row * 128 + kc + 4);
        __align__(16) short s[8] = {f2bf(v0.x), f2bf(v0.y), f2bf(v0.z), f2bf(v0.w),
                                    f2bf(v1.x), f2bf(v1.y), f2bf(v1.z), f2bf(v1.w)};
        *(int4*)(xrow + (size_t)row * 128 + kc) = *(const int4*)s;
        size_t pidx = ((size_t)(row >> 4) * 16 + (kc >> 3)) * 128 + (size_t)(row & 15) * 8;
        *(int4*)(xpack + pidx) = *(const int4*)s;
        return;
    }
    int u = t - N_NODES * 16;
    if (u >= 4 * 32768) return;
    const int w = u >> 15;        // which weight
    const int t2 = u & 32767;
    const float* W; short* P; int K, NC;
    if (w == 0)      { W = Wl1; P = wl1p; K = 128; NC = 256; }
    else if (w == 1) { W = Wr1; P = wr1p; K = 128; NC = 256; }
    else if (w == 2) { W = Wl2; P = wl2p; K = 256; NC = 128; }
    else             { W = Wr2; P = wr2p; K = 256; NC = 128; }
    int k = t2 / NC, c = t2 % NC;
    P[((size_t)(c >> 4) * (K >> 3) + (k >> 3)) * 128 + (size_t)(c & 15) * 8 + (k & 7)] = f2bf(W[t2]);
}

// ---------------- mean aggregation over 128-dim bf16 rows (round-4 optimum) ----------------
// 256 threads = 4 waves = 4 nodes per block; wave = 4 groups of 16 lanes;
// group g handles edges j = s+g+4t with 2x branchless unroll (8 rows in flight/wave).
// MODE 0: write packed bf16 (GEMM A-operand). MODE 1: outf[node] += mean (f32 RMW).
template<int MODE>
__global__ __launch_bounds__(256)
void aggregate128_kernel(const short* __restrict__ feat, const int* __restrict__ offsets,
                         const int* __restrict__ srcs,
                         short* __restrict__ outpack, float* __restrict__ outf) {
    int node = blockIdx.x * 4 + (threadIdx.x >> 6);
    if (node >= N_NODES) return;
    const int lane = threadIdx.x & 63;
    const int g = lane >> 4, p = lane & 15;
    const int s = offsets[node], e = offsets[node + 1];
    const float inv = 1.0f / (float)max(e - s, 1);
    float acc[8] = {0.f, 0.f, 0.f, 0.f, 0.f, 0.f, 0.f, 0.f};
    for (int j = s + g; j < e; j += 8) {
        const int j2 = j + 4;
        const bool h2 = (j2 < e);
        const int i0 = srcs[j];
        const int i1 = h2 ? srcs[j2] : i0;
        const uint4 w0 = *(const uint4*)(feat + (size_t)i0 * 128 + p * 8);
        const uint4 w1 = *(const uint4*)(feat + (size_t)i1 * 128 + p * 8);
        acc[0] += bf2f_lo(w0.x); acc[1] += bf2f_hi(w0.x);
        acc[2] += bf2f_lo(w0.y); acc[3] += bf2f_hi(w0.y);
        acc[4] += bf2f_lo(w0.z); acc[5] += bf2f_hi(w0.z);
        acc[6] += bf2f_lo(w0.w); acc[7] += bf2f_hi(w0.w);
        if (h2) {
            acc[0] += bf2f_lo(w1.x); acc[1] += bf2f_hi(w1.x);
            acc[2] += bf2f_lo(w1.y); acc[3] += bf2f_hi(w1.y);
            acc[4] += bf2f_lo(w1.z); acc[5] += bf2f_hi(w1.z);
            acc[6] += bf2f_lo(w1.w); acc[7] += bf2f_hi(w1.w);
        }
    }
    #pragma unroll
    for (int t = 0; t < 8; ++t) acc[t] += __shfl_xor(acc[t], 16, 64);
    #pragma unroll
    for (int t = 0; t < 8; ++t) acc[t] += __shfl_xor(acc[t], 32, 64);
    if (g != 0) return;
    if (MODE == 0) {
        __align__(16) short r[8];
        #pragma unroll
        for (int t = 0; t < 8; ++t) r[t] = f2bf(acc[t] * inv);
        size_t pidx = ((size_t)(node >> 4) * 16 + p) * 128 + (size_t)(node & 15) * 8;
        *(int4*)(outpack + pidx) = *(const int4*)r;
    } else {
        float* o = outf + (size_t)node * 128 + p * 8;
        float4 q0 = *(const float4*)o;
        float4 q1 = *(const float4*)(o + 4);
        q0.x += acc[0] * inv; q0.y += acc[1] * inv; q0.z += acc[2] * inv; q0.w += acc[3] * inv;
        q1.x += acc[4] * inv; q1.y += acc[5] * inv; q1.z += acc[6] * inv; q1.w += acc[7] * inv;
        *(float4*)o = q0;
        *(float4*)(o + 4) = q1;
    }
}

// ---------------- layer-1 GEMM: h = relu(A0@B0 + A1@B1 + bias), packed bf16 out ----------------
// wave tile 64 rows x 128 cols; linear grid with XCD-pair swizzle (rowBlk, colHalf).
__global__ __launch_bounds__(256)
void gemm1_kernel(const short* __restrict__ A0, const short* __restrict__ A1,
                  const short* __restrict__ B0, const short* __restrict__ B1,
                  const float* __restrict__ bias, short* __restrict__ opack) {
    constexpr int KB = 16, KS = 4, S = 8;   // k-chunks/row, steps/phase, total steps
    __shared__ float sC[4][32][132];
    int rowBlk, colHalf;
    if (!xcd_map(blockIdx.x, rowBlk, colHalf)) return;
    const int tid = threadIdx.x, wave = tid >> 6, lane = tid & 63;
    const int lhi = lane >> 4, llo = lane & 15;
    const int rowBase = rowBlk * 256 + wave * 64;
    const int colBase = colHalf * 128;
    const int rowTile = rowBase >> 4, colTile = colBase >> 4;

    f32x4 acc[4][8];
    #pragma unroll
    for (int i = 0; i < 4; ++i)
        #pragma unroll
        for (int j = 0; j < 8; ++j)
            #pragma unroll
            for (int r = 0; r < 4; ++r) acc[i][j][r] = 0.f;

    bf16x8 a[4];
    #pragma unroll
    for (int i = 0; i < 4; ++i)
        a[i] = *(const bf16x8*)(A0 + ((size_t)(rowTile + i) * KB + lhi) * 128 + (size_t)llo * 8);

    #pragma unroll
    for (int s = 0; s < S; ++s) {
        const short* B = (s >= KS) ? B1 : B0;
        const int kb = (s - (s >= KS ? KS : 0)) * 4 + lhi;
        bf16x8 b[8];
        #pragma unroll
        for (int j = 0; j < 8; ++j)
            b[j] = *(const bf16x8*)(B + ((size_t)(colTile + j) * KB + kb) * 128 + (size_t)llo * 8);
        bf16x8 an[4];
        if (s + 1 < S) {
            const int s1 = s + 1;
            const short* A = (s1 >= KS) ? A1 : A0;
            const int kb1 = (s1 - (s1 >= KS ? KS : 0)) * 4 + lhi;
            #pragma unroll
            for (int i = 0; i < 4; ++i)
                an[i] = *(const bf16x8*)(A + ((size_t)(rowTile + i) * KB + kb1) * 128 + (size_t)llo * 8);
        }
        #pragma unroll
        for (int i = 0; i < 4; ++i)
            #pragma unroll
            for (int j = 0; j < 8; ++j)
                acc[i][j] = __builtin_amdgcn_mfma_f32_16x16x32_bf16(a[i], b[j], acc[i][j], 0, 0, 0);
        if (s + 1 < S) {
            #pragma unroll
            for (int i = 0; i < 4; ++i) a[i] = an[i];
        }
    }

    #pragma unroll
    for (int j = 0; j < 8; ++j) {
        float bv = bias[colBase + j * 16 + llo];
        #pragma unroll
        for (int i = 0; i < 4; ++i)
            #pragma unroll
            for (int r = 0; r < 4; ++r)
                acc[i][j][r] = fmaxf(acc[i][j][r] + bv, 0.f);
    }

    #pragma unroll
    for (int half = 0; half < 2; ++half) {
        #pragma unroll
        for (int i2 = 0; i2 < 2; ++i2) {
            const int i = half * 2 + i2;
            #pragma unroll
            for (int j = 0; j < 8; ++j)
                #pragma unroll
                for (int r = 0; r < 4; ++r)
                    sC[wave][i2 * 16 + lhi * 4 + r][j * 16 + llo] = acc[i][j][r];
        }
        #pragma unroll
        for (int it = 0; it < 8; ++it) {
            const int r = it * 4 + (lane >> 4);
            const int c = (lane & 15) * 8;
            const int grow = rowBase + half * 32 + r;
            if (grow < N_NODES) {
                float4 v0 = *(const float4*)&sC[wave][r][c];
                float4 v1 = *(const float4*)&sC[wave][r][c + 4];
                __align__(16) short sv[8] = {f2bf(v0.x), f2bf(v0.y), f2bf(v0.z), f2bf(v0.w),
                                             f2bf(v1.x), f2bf(v1.y), f2bf(v1.z), f2bf(v1.w)};
                size_t pidx = ((size_t)(grow >> 4) * 32 + ((colBase + c) >> 3)) * 128
                            + (size_t)(grow & 15) * 8;
                *(int4*)(opack + pidx) = *(const int4*)sv;
            }
        }
    }
}

// ---------------- layer-2 dual-output GEMM: p = A@B0 (bf16 rows); q = A@B1 + bias (f32) ----------------
// wave tile 64 rows x 64 cols of BOTH outputs; linear grid with XCD-pair swizzle.
__global__ __launch_bounds__(256)
void gemm2_kernel(const short* __restrict__ A, const short* __restrict__ B0,
                  const short* __restrict__ B1, const float* __restrict__ bias,
                  short* __restrict__ prow, float* __restrict__ qf32) {
    constexpr int KB = 32, S = 8;
    __shared__ float sC[4][32][68];
    int rowBlk, colHalf;
    if (!xcd_map(blockIdx.x, rowBlk, colHalf)) return;
    const int tid = threadIdx.x, wave = tid >> 6, lane = tid & 63;
    const int lhi = lane >> 4, llo = lane & 15;
    const int rowBase = rowBlk * 256 + wave * 64;
    const int colBase = colHalf * 64;
    const int rowTile = rowBase >> 4, colTile = colBase >> 4;

    f32x4 accp[4][4], accq[4][4];
    #pragma unroll
    for (int i = 0; i < 4; ++i)
        #pragma unroll
        for (int j = 0; j < 4; ++j)
            #pragma unroll
            for (int r = 0; r < 4; ++r) { accp[i][j][r] = 0.f; accq[i][j][r] = 0.f; }

    bf16x8 a[4];
    #pragma unroll
    for (int i = 0; i < 4; ++i)
        a[i] = *(const bf16x8*)(A + ((size_t)(rowTile + i) * KB + lhi) * 128 + (size_t)llo * 8);

    #pragma unroll
    for (int s = 0; s < S; ++s) {
        const int kb = s * 4 + lhi;
        bf16x8 b0[4], b1[4];
        #pragma unroll
        for (int j = 0; j < 4; ++j) {
            b0[j] = *(const bf16x8*)(B0 + ((size_t)(colTile + j) * KB + kb) * 128 + (size_t)llo * 8);
            b1[j] = *(const bf16x8*)(B1 + ((size_t)(colTile + j) * KB + kb) * 128 + (size_t)llo * 8);
        }
        bf16x8 an[4];
        if (s + 1 < S) {
            const int kb1 = (s + 1) * 4 + lhi;
            #pragma unroll
            for (int i = 0; i < 4; ++i)
                an[i] = *(const bf16x8*)(A + ((size_t)(rowTile + i) * KB + kb1) * 128 + (size_t)llo * 8);
        }
        #pragma unroll
        for (int i = 0; i < 4; ++i)
            #pragma unroll
            for (int j = 0; j < 4; ++j) {
                accp[i][j] = __builtin_amdgcn_mfma_f32_16x16x32_bf16(a[i], b0[j], accp[i][j], 0, 0, 0);
                accq[i][j] = __builtin_amdgcn_mfma_f32_16x16x32_bf16(a[i], b1[j], accq[i][j], 0, 0, 0);
            }
        if (s + 1 < S) {
            #pragma unroll
            for (int i = 0; i < 4; ++i) a[i] = an[i];
        }
    }

    // p epilogue: bf16 row-major
    #pragma unroll
    for (int half = 0; half < 2; ++half) {
        #pragma unroll
        for (int i2 = 0; i2 < 2; ++i2) {
            const int i = half * 2 + i2;
            #pragma unroll
            for (int j = 0; j < 4; ++j)
                #pragma unroll
                for (int r = 0; r < 4; ++r)
                    sC[wave][i2 * 16 + lhi * 4 + r][j * 16 + llo] = accp[i][j][r];
        }
        #pragma unroll
        for (int it = 0; it < 4; ++it) {
            const int r = it * 8 + (lane >> 3);
            const int c = (lane & 7) * 8;
            const int grow = rowBase + half * 32 + r;
            if (grow < N_NODES) {
                float4 v0 = *(const float4*)&sC[wave][r][c];
                float4 v1 = *(const float4*)&sC[wave][r][c + 4];
                __align__(16) short sv[8] = {f2bf(v0.x), f2bf(v0.y), f2bf(v0.z), f2bf(v0.w),
                                             f2bf(v1.x), f2bf(v1.y), f2bf(v1.z), f2bf(v1.w)};
                *(int4*)(prow + (size_t)grow * 128 + colBase + c) = *(const int4*)sv;
            }
        }
    }

    // q epilogue: f32 + bias
    #pragma unroll
    for (int j = 0; j < 4; ++j) {
        float bv = bias[colBase + j * 16 + llo];
        #pragma unroll
        for (int i = 0; i < 4; ++i)
            #pragma unroll
            for (int r = 0; r < 4; ++r) accq[i][j][r] += bv;
    }
    #pragma unroll
    for (int half = 0; half < 2; ++half) {
        #pragma unroll
        for (int i2 = 0; i2 < 2; ++i2) {
            const int i = half * 2 + i2;
            #pragma unroll
            for (int j = 0; j < 4; ++j)
                #pragma unroll
                for (int r = 0; r < 4; ++r)
                    sC[wave][i2 * 16 + lhi * 4 + r][j * 16 + llo] = accq[i][j][r];
        }
        #pragma unroll
        for (int it = 0; it < 4; ++it) {
            const int r = it * 8 + (lane >> 3);
            const int c = (lane & 7) * 8;
            const int grow = rowBase + half * 32 + r;
            if (grow < N_NODES) {
                float4 v0 = *(const float4*)&sC[wave][r][c];
                float4 v1 = *(const float4*)&sC[wave][r][c + 4];
                *(float4*)(qf32 + (size_t)grow * 128 + colBase + c) = v0;
                *(float4*)(qf32 + (size_t)grow * 128 + colBase + c + 4) = v1;
            }
        }
    }
}

extern "C" void kernel_launch(void* const* d_in, const int* in_sizes, int n_in,
                              void* d_out, int out_size, void* d_ws, size_t ws_size,
                              hipStream_t stream) {
    const float* x   = (const float*)d_in[0];
    const int*   ei  = (const int*)d_in[1];
    const float* Wl1 = (const float*)d_in[2];
    const float* b1  = (const float*)d_in[3];
    const float* Wr1 = (const float*)d_in[4];
    const float* Wl2 = (const float*)d_in[5];
    const float* b2  = (const float*)d_in[6];
    const float* Wr2 = (const float*)d_in[7];
    const int E = in_sizes[1] / 2;
    const int* src = ei;
    const int* dst = ei + E;

    // workspace layout
    short* h_pack = (short*)d_ws;                   // NPAD*256
    short* agg1p  = h_pack + (size_t)NPAD * 256;    // NPAD*128
    short* x_row  = agg1p  + (size_t)NPAD * 128;    // NPAD*128
    short* x_pack = x_row  + (size_t)NPAD * 128;    // NPAD*128
    short* p_row  = x_pack + (size_t)NPAD * 128;    // NPAD*128
    short* wl1p   = p_row  + (size_t)NPAD * 128;    // 32768
    short* wr1p   = wl1p + 32768;
    short* wl2p   = wr1p + 32768;
    short* wr2p   = wl2p + 32768;
    int* bucket_cnt    = (int*)(wr2p + 32768);      // NBLK+1
    int* bucket_base   = bucket_cnt + NBLK + 1;     // NBLK+1
    int* bucket_cursor = bucket_base + NBLK + 1;    // NBLK+1
    int* offsets       = bucket_cursor + NBLK + 1;  // N+1
    unsigned int* bin  = (unsigned int*)(offsets + N_NODES + 1); // E
    int* sorted        = (int*)(bin + E);           // E

    const int nbin = (E + 4095) / 4096;

    // CSR build (binned two-pass counting sort)
    hipMemsetAsync(bucket_cnt, 0, (NBLK + 1) * sizeof(int), stream);
    cbuck_kernel<<<nbin, 256, 0, stream>>>(dst, bucket_cnt, E);
    scan391_kernel<<<1, 512, 0, stream>>>(bucket_cnt, bucket_base, bucket_cursor, offsets);
    bin_kernel<<<nbin, 256, 0, stream>>>(src, dst, bucket_cursor, bin, E);
    place_kernel<<<NBLK, 256, 0, stream>>>(bin, bucket_base, offsets, sorted);

    // fused bf16 conversions / packing (x + all 4 weights)
    prep_kernel<<<(N_NODES * 16 + 4 * 32768 + 255) / 256, 256, 0, stream>>>(
        x, x_row, x_pack, Wl1, Wr1, Wl2, Wr2, wl1p, wr1p, wl2p, wr2p);

    // layer 1: agg(x) -> h = relu([mean,x]@[Wl1;Wr1] + b1) (packed)
    aggregate128_kernel<0><<<(N_NODES + 3) / 4, 256, 0, stream>>>(x_row, offsets, sorted, agg1p, nullptr);
    gemm1_kernel<<<GEMM_GRID, 256, 0, stream>>>(agg1p, x_pack, wl1p, wr1p, b1, h_pack);

    // layer 2 (commuted): p = h@Wl2; q = h@Wr2 + b2 -> d_out; d_out += mean(p)
    gemm2_kernel<<<GEMM_GRID, 256, 0, stream>>>(h_pack, wl2p, wr2p, b2, p_row, (float*)d_out);
    aggregate128_kernel<1><<<(N_NODES + 3) / 4, 256, 0, stream>>>(p_row, offsets, sorted, nullptr, (float*)d_out);
}

// Round 9
// 281.366 us; speedup vs baseline: 2.8896x; 1.0473x over previous
//
#include <hip/hip_runtime.h>

#define N_NODES 100000
#define NPAD 100096   // 391 * 256
#define NBLK 391      // dst buckets of 256 nodes / row blocks

using bf16x8 = __attribute__((ext_vector_type(8))) short;
using f32x4  = __attribute__((ext_vector_type(4))) float;
using f32x2  = __attribute__((ext_vector_type(2))) float;

__device__ inline short f2bf(float f) {               // RNE f32 -> bf16
    unsigned int u = __float_as_uint(f);
    unsigned int r = (u + 0x7FFFu + ((u >> 16) & 1u)) >> 16;
    return (short)r;
}
__device__ inline float bf2f_lo(unsigned int w) { return __uint_as_float(w << 16); }
__device__ inline float bf2f_hi(unsigned int w) { return __uint_as_float(w & 0xFFFF0000u); }

// map linear bid -> (rowBlk, colHalf) such that both colHalves of a row block
// land on the SAME XCD (round-robin assumption; perf-only heuristic).
__device__ inline bool xcd_map(int bid, int& row, int& col) {
    const int RP = (NBLK + 7) / 8;           // 49 row-blocks per XCD
    const int xcd = bid & 7;
    const int i = bid >> 3;
    row = xcd * RP + (i >> 1);
    col = i & 1;
    return row < NBLK;
}
#define GEMM_GRID (8 * 2 * ((NBLK + 7) / 8))   // 784

// ---------------- pass 0: bucket histogram (LDS pre-reduce) ----------------
__global__ __launch_bounds__(256)
void cbuck_kernel(const int* __restrict__ dst, int* __restrict__ bucket_cnt, int E) {
    __shared__ int cnt[NBLK];
    const int tid = threadIdx.x;
    for (int i = tid; i < NBLK; i += 256) cnt[i] = 0;
    __syncthreads();
    const int e0 = blockIdx.x * 4096;
    #pragma unroll
    for (int k = 0; k < 16; ++k) {
        int e = e0 + k * 256 + tid;
        if (e < E) atomicAdd(&cnt[dst[e] >> 8], 1);
    }
    __syncthreads();
    for (int i = tid; i < NBLK; i += 256)
        if (cnt[i]) atomicAdd(&bucket_cnt[i], cnt[i]);
}

// ---------------- pass 1: scan of 391 bucket counts ----------------
__global__ void scan391_kernel(const int* __restrict__ bucket_cnt, int* __restrict__ bucket_base,
                               int* __restrict__ bucket_cursor, int* __restrict__ offsets) {
    __shared__ int s[512];
    int t = threadIdx.x;
    int v = (t < NBLK) ? bucket_cnt[t] : 0;
    s[t] = v;
    __syncthreads();
    #pragma unroll
    for (int off = 1; off < 512; off <<= 1) {
        int u = (t >= off) ? s[t - off] : 0;
        __syncthreads();
        s[t] += u;
        __syncthreads();
    }
    if (t < NBLK) {
        int excl = s[t] - v;
        bucket_base[t] = excl;
        bucket_cursor[t] = excl;
    }
    if (t == NBLK - 1) {
        bucket_base[NBLK] = s[t];
        offsets[N_NODES] = s[t];      // = E
    }
}

// ---------------- pass 2: bin edges by dst>>8, dense packed writes ----------------
__global__ __launch_bounds__(256)
void bin_kernel(const int* __restrict__ src, const int* __restrict__ dst,
                int* __restrict__ bucket_cursor, unsigned int* __restrict__ bin, int E) {
    __shared__ int cnt[NBLK];
    __shared__ int base_l[NBLK];
    const int tid = threadIdx.x;
    const int e0 = blockIdx.x * 4096;
    for (int i = tid; i < NBLK; i += 256) cnt[i] = 0;
    __syncthreads();
    int myb[16]; unsigned myv[16];
    #pragma unroll
    for (int k = 0; k < 16; ++k) {
        int e = e0 + k * 256 + tid;
        if (e < E) {
            int d = dst[e];
            myb[k] = d >> 8;
            myv[k] = (unsigned)src[e] | ((unsigned)(d & 255) << 20);
            atomicAdd(&cnt[myb[k]], 1);
        } else myb[k] = -1;
    }
    __syncthreads();
    for (int i = tid; i < NBLK; i += 256) {
        int c = cnt[i];
        base_l[i] = c ? atomicAdd(&bucket_cursor[i], c) : 0;
        cnt[i] = 0;
    }
    __syncthreads();
    #pragma unroll
    for (int k = 0; k < 16; ++k) {
        if (myb[k] >= 0) {
            int slot = base_l[myb[k]] + atomicAdd(&cnt[myb[k]], 1);
            bin[slot] = myv[k];
        }
    }
}

// ---------------- pass 3: per-bucket place; also emits per-node offsets ----------------
__global__ __launch_bounds__(256)
void place_kernel(const unsigned int* __restrict__ bin, const int* __restrict__ bucket_base,
                  int* __restrict__ offsets, int* __restrict__ sorted) {
    __shared__ int cnt[256];
    __shared__ int cur[256];
    __shared__ int wsum[4];
    const int b = blockIdx.x, tid = threadIdx.x;
    const int lane = tid & 63, wave = tid >> 6;
    const int s = bucket_base[b];
    const int e = bucket_base[b + 1];
    cnt[tid] = 0;
    __syncthreads();
    for (int i = s + tid; i < e; i += 256) atomicAdd(&cnt[bin[i] >> 20], 1);
    __syncthreads();
    int v = cnt[tid];
    int x = v;
    #pragma unroll
    for (int off = 1; off < 64; off <<= 1) {
        int t = __shfl_up(x, off, 64);
        if (lane >= off) x += t;
    }
    if (lane == 63) wsum[wave] = x;
    __syncthreads();
    int woff = 0;
    #pragma unroll
    for (int w = 0; w < 4; ++w) if (w < wave) woff += wsum[w];
    int excl = s + woff + x - v;
    cur[tid] = excl;
    int node = b * 256 + tid;
    if (node < N_NODES) offsets[node] = excl;
    __syncthreads();
    for (int i = s + tid; i < e; i += 256) {
        unsigned w = bin[i];
        int p = atomicAdd(&cur[w >> 20], 1);
        sorted[p] = (int)(w & 0xFFFFFu);
    }
}

// ---------------- fused prep: cast x (fp8 row table + bf16 packed) AND pack 4 weights ----------------
__global__ __launch_bounds__(256)
void prep_kernel(const float* __restrict__ x, unsigned char* __restrict__ xfp8,
                 short* __restrict__ xpack,
                 const float* __restrict__ Wl1, const float* __restrict__ Wr1,
                 const float* __restrict__ Wl2, const float* __restrict__ Wr2,
                 short* __restrict__ wl1p, short* __restrict__ wr1p,
                 short* __restrict__ wl2p, short* __restrict__ wr2p) {
    int t = blockIdx.x * 256 + threadIdx.x;
    if (t < N_NODES * 16) {
        int row = t >> 4;
        int kc = (t & 15) << 3;
        const float4 v0 = *(const float4*)(x + (size_t)row * 128 + kc);
        const float4 v1 = *(const float4*)(x + (size_t)row * 128 + kc + 4);
        // bf16 fragment-packed (GEMM A-operand + low-degree gather fallback)
        __align__(16) short s[8] = {f2bf(v0.x), f2bf(v0.y), f2bf(v0.z), f2bf(v0.w),
                                    f2bf(v1.x), f2bf(v1.y), f2bf(v1.z), f2bf(v1.w)};
        size_t pidx = ((size_t)(row >> 4) * 16 + (kc >> 3)) * 128 + (size_t)(row & 15) * 8;
        *(int4*)(xpack + pidx) = *(const int4*)s;
        // fp8 e4m3 row table (hot gather path)
        int w0 = __builtin_amdgcn_cvt_pk_fp8_f32(v0.x, v0.y, 0, 0);
        w0     = __builtin_amdgcn_cvt_pk_fp8_f32(v0.z, v0.w, w0, 1);
        int w1 = __builtin_amdgcn_cvt_pk_fp8_f32(v1.x, v1.y, 0, 0);
        w1     = __builtin_amdgcn_cvt_pk_fp8_f32(v1.z, v1.w, w1, 1);
        *(uint2*)(xfp8 + (size_t)row * 128 + kc) = make_uint2((unsigned)w0, (unsigned)w1);
        return;
    }
    int u = t - N_NODES * 16;
    if (u >= 4 * 32768) return;
    const int w = u >> 15;        // which weight
    const int t2 = u & 32767;
    const float* W; short* P; int K, NC;
    if (w == 0)      { W = Wl1; P = wl1p; K = 128; NC = 256; }
    else if (w == 1) { W = Wr1; P = wr1p; K = 128; NC = 256; }
    else if (w == 2) { W = Wl2; P = wl2p; K = 256; NC = 128; }
    else             { W = Wr2; P = wr2p; K = 256; NC = 128; }
    int k = t2 / NC, c = t2 % NC;
    P[((size_t)(c >> 4) * (K >> 3) + (k >> 3)) * 128 + (size_t)(c & 15) * 8 + (k & 7)] = f2bf(W[t2]);
}

// ---------------- layer-1 mean aggregation: fp8 gather, deg-gated bf16 fallback ----------------
// 256 threads = 4 waves = 4 nodes/block; wave = 4 groups of 16 lanes, 2x branchless unroll.
// deg >= 8: fp8 rows (128 B) from xfp8 (HW cvt_pk_f32_fp8 decode).
// deg <  8: bf16 rows gathered from the fragment-packed x (error can't average out).
// Output: packed bf16 GEMM A-operand.
__global__ __launch_bounds__(256)
void aggregate_x_kernel(const unsigned char* __restrict__ xfp8, const short* __restrict__ xpack,
                        const int* __restrict__ offsets, const int* __restrict__ srcs,
                        short* __restrict__ outpack) {
    int node = blockIdx.x * 4 + (threadIdx.x >> 6);
    if (node >= N_NODES) return;
    const int lane = threadIdx.x & 63;
    const int g = lane >> 4, p = lane & 15;
    const int s = offsets[node], e = offsets[node + 1];
    const int deg = e - s;
    const float inv = 1.0f / (float)max(deg, 1);
    float acc[8] = {0.f, 0.f, 0.f, 0.f, 0.f, 0.f, 0.f, 0.f};
    if (deg >= 8) {
        for (int j = s + g; j < e; j += 8) {
            const int j2 = j + 4;
            const bool h2 = (j2 < e);
            const int i0 = srcs[j];
            const int i1 = h2 ? srcs[j2] : i0;
            const uint2 w0 = *(const uint2*)(xfp8 + (size_t)i0 * 128 + p * 8);
            const uint2 w1 = *(const uint2*)(xfp8 + (size_t)i1 * 128 + p * 8);
            f32x2 c0 = __builtin_amdgcn_cvt_pk_f32_fp8((int)w0.x, 0);
            f32x2 c1 = __builtin_amdgcn_cvt_pk_f32_fp8((int)w0.x, 1);
            f32x2 c2 = __builtin_amdgcn_cvt_pk_f32_fp8((int)w0.y, 0);
            f32x2 c3 = __builtin_amdgcn_cvt_pk_f32_fp8((int)w0.y, 1);
            acc[0] += c0[0]; acc[1] += c0[1]; acc[2] += c1[0]; acc[3] += c1[1];
            acc[4] += c2[0]; acc[5] += c2[1]; acc[6] += c3[0]; acc[7] += c3[1];
            if (h2) {
                f32x2 d0 = __builtin_amdgcn_cvt_pk_f32_fp8((int)w1.x, 0);
                f32x2 d1 = __builtin_amdgcn_cvt_pk_f32_fp8((int)w1.x, 1);
                f32x2 d2 = __builtin_amdgcn_cvt_pk_f32_fp8((int)w1.y, 0);
                f32x2 d3 = __builtin_amdgcn_cvt_pk_f32_fp8((int)w1.y, 1);
                acc[0] += d0[0]; acc[1] += d0[1]; acc[2] += d1[0]; acc[3] += d1[1];
                acc[4] += d2[0]; acc[5] += d2[1]; acc[6] += d3[0]; acc[7] += d3[1];
            }
        }
    } else {
        for (int j = s + g; j < e; j += 4) {
            const int idx = srcs[j];
            const uint4 w = *(const uint4*)(xpack + ((size_t)(idx >> 4) * 16 + p) * 128
                                                  + (size_t)(idx & 15) * 8);
            acc[0] += bf2f_lo(w.x); acc[1] += bf2f_hi(w.x);
            acc[2] += bf2f_lo(w.y); acc[3] += bf2f_hi(w.y);
            acc[4] += bf2f_lo(w.z); acc[5] += bf2f_hi(w.z);
            acc[6] += bf2f_lo(w.w); acc[7] += bf2f_hi(w.w);
        }
    }
    #pragma unroll
    for (int t = 0; t < 8; ++t) acc[t] += __shfl_xor(acc[t], 16, 64);
    #pragma unroll
    for (int t = 0; t < 8; ++t) acc[t] += __shfl_xor(acc[t], 32, 64);
    if (g != 0) return;
    __align__(16) short r[8];
    #pragma unroll
    for (int t = 0; t < 8; ++t) r[t] = f2bf(acc[t] * inv);
    size_t pidx = ((size_t)(node >> 4) * 16 + p) * 128 + (size_t)(node & 15) * 8;
    *(int4*)(outpack + pidx) = *(const int4*)r;
}

// ---------------- layer-2 mean aggregation over 128-dim bf16 rows (round-4 optimum) ----------------
// outf[node] += mean (f32 RMW into d_out).
__global__ __launch_bounds__(256)
void aggregate_p_kernel(const short* __restrict__ feat, const int* __restrict__ offsets,
                        const int* __restrict__ srcs, float* __restrict__ outf) {
    int node = blockIdx.x * 4 + (threadIdx.x >> 6);
    if (node >= N_NODES) return;
    const int lane = threadIdx.x & 63;
    const int g = lane >> 4, p = lane & 15;
    const int s = offsets[node], e = offsets[node + 1];
    const float inv = 1.0f / (float)max(e - s, 1);
    float acc[8] = {0.f, 0.f, 0.f, 0.f, 0.f, 0.f, 0.f, 0.f};
    for (int j = s + g; j < e; j += 8) {
        const int j2 = j + 4;
        const bool h2 = (j2 < e);
        const int i0 = srcs[j];
        const int i1 = h2 ? srcs[j2] : i0;
        const uint4 w0 = *(const uint4*)(feat + (size_t)i0 * 128 + p * 8);
        const uint4 w1 = *(const uint4*)(feat + (size_t)i1 * 128 + p * 8);
        acc[0] += bf2f_lo(w0.x); acc[1] += bf2f_hi(w0.x);
        acc[2] += bf2f_lo(w0.y); acc[3] += bf2f_hi(w0.y);
        acc[4] += bf2f_lo(w0.z); acc[5] += bf2f_hi(w0.z);
        acc[6] += bf2f_lo(w0.w); acc[7] += bf2f_hi(w0.w);
        if (h2) {
            acc[0] += bf2f_lo(w1.x); acc[1] += bf2f_hi(w1.x);
            acc[2] += bf2f_lo(w1.y); acc[3] += bf2f_hi(w1.y);
            acc[4] += bf2f_lo(w1.z); acc[5] += bf2f_hi(w1.z);
            acc[6] += bf2f_lo(w1.w); acc[7] += bf2f_hi(w1.w);
        }
    }
    #pragma unroll
    for (int t = 0; t < 8; ++t) acc[t] += __shfl_xor(acc[t], 16, 64);
    #pragma unroll
    for (int t = 0; t < 8; ++t) acc[t] += __shfl_xor(acc[t], 32, 64);
    if (g != 0) return;
    float* o = outf + (size_t)node * 128 + p * 8;
    float4 q0 = *(const float4*)o;
    float4 q1 = *(const float4*)(o + 4);
    q0.x += acc[0] * inv; q0.y += acc[1] * inv; q0.z += acc[2] * inv; q0.w += acc[3] * inv;
    q1.x += acc[4] * inv; q1.y += acc[5] * inv; q1.z += acc[6] * inv; q1.w += acc[7] * inv;
    *(float4*)o = q0;
    *(float4*)(o + 4) = q1;
}

// ---------------- layer-1 GEMM: h = relu(A0@B0 + A1@B1 + bias), packed bf16 out ----------------
// wave tile 64 rows x 128 cols; linear grid with XCD-pair swizzle (rowBlk, colHalf).
__global__ __launch_bounds__(256)
void gemm1_kernel(const short* __restrict__ A0, const short* __restrict__ A1,
                  const short* __restrict__ B0, const short* __restrict__ B1,
                  const float* __restrict__ bias, short* __restrict__ opack) {
    constexpr int KB = 16, KS = 4, S = 8;   // k-chunks/row, steps/phase, total steps
    __shared__ float sC[4][32][132];
    int rowBlk, colHalf;
    if (!xcd_map(blockIdx.x, rowBlk, colHalf)) return;
    const int tid = threadIdx.x, wave = tid >> 6, lane = tid & 63;
    const int lhi = lane >> 4, llo = lane & 15;
    const int rowBase = rowBlk * 256 + wave * 64;
    const int colBase = colHalf * 128;
    const int rowTile = rowBase >> 4, colTile = colBase >> 4;

    f32x4 acc[4][8];
    #pragma unroll
    for (int i = 0; i < 4; ++i)
        #pragma unroll
        for (int j = 0; j < 8; ++j)
            #pragma unroll
            for (int r = 0; r < 4; ++r) acc[i][j][r] = 0.f;

    bf16x8 a[4];
    #pragma unroll
    for (int i = 0; i < 4; ++i)
        a[i] = *(const bf16x8*)(A0 + ((size_t)(rowTile + i) * KB + lhi) * 128 + (size_t)llo * 8);

    #pragma unroll
    for (int s = 0; s < S; ++s) {
        const short* B = (s >= KS) ? B1 : B0;
        const int kb = (s - (s >= KS ? KS : 0)) * 4 + lhi;
        bf16x8 b[8];
        #pragma unroll
        for (int j = 0; j < 8; ++j)
            b[j] = *(const bf16x8*)(B + ((size_t)(colTile + j) * KB + kb) * 128 + (size_t)llo * 8);
        bf16x8 an[4];
        if (s + 1 < S) {
            const int s1 = s + 1;
            const short* A = (s1 >= KS) ? A1 : A0;
            const int kb1 = (s1 - (s1 >= KS ? KS : 0)) * 4 + lhi;
            #pragma unroll
            for (int i = 0; i < 4; ++i)
                an[i] = *(const bf16x8*)(A + ((size_t)(rowTile + i) * KB + kb1) * 128 + (size_t)llo * 8);
        }
        #pragma unroll
        for (int i = 0; i < 4; ++i)
            #pragma unroll
            for (int j = 0; j < 8; ++j)
                acc[i][j] = __builtin_amdgcn_mfma_f32_16x16x32_bf16(a[i], b[j], acc[i][j], 0, 0, 0);
        if (s + 1 < S) {
            #pragma unroll
            for (int i = 0; i < 4; ++i) a[i] = an[i];
        }
    }

    #pragma unroll
    for (int j = 0; j < 8; ++j) {
        float bv = bias[colBase + j * 16 + llo];
        #pragma unroll
        for (int i = 0; i < 4; ++i)
            #pragma unroll
            for (int r = 0; r < 4; ++r)
                acc[i][j][r] = fmaxf(acc[i][j][r] + bv, 0.f);
    }

    #pragma unroll
    for (int half = 0; half < 2; ++half) {
        #pragma unroll
        for (int i2 = 0; i2 < 2; ++i2) {
            const int i = half * 2 + i2;
            #pragma unroll
            for (int j = 0; j < 8; ++j)
                #pragma unroll
                for (int r = 0; r < 4; ++r)
                    sC[wave][i2 * 16 + lhi * 4 + r][j * 16 + llo] = acc[i][j][r];
        }
        #pragma unroll
        for (int it = 0; it < 8; ++it) {
            const int r = it * 4 + (lane >> 4);
            const int c = (lane & 15) * 8;
            const int grow = rowBase + half * 32 + r;
            if (grow < N_NODES) {
                float4 v0 = *(const float4*)&sC[wave][r][c];
                float4 v1 = *(const float4*)&sC[wave][r][c + 4];
                __align__(16) short sv[8] = {f2bf(v0.x), f2bf(v0.y), f2bf(v0.z), f2bf(v0.w),
                                             f2bf(v1.x), f2bf(v1.y), f2bf(v1.z), f2bf(v1.w)};
                size_t pidx = ((size_t)(grow >> 4) * 32 + ((colBase + c) >> 3)) * 128
                            + (size_t)(grow & 15) * 8;
                *(int4*)(opack + pidx) = *(const int4*)sv;
            }
        }
    }
}

// ---------------- layer-2 dual-output GEMM: p = A@B0 (bf16 rows); q = A@B1 + bias (f32) ----------------
// wave tile 64 rows x 64 cols of BOTH outputs; linear grid with XCD-pair swizzle.
__global__ __launch_bounds__(256)
void gemm2_kernel(const short* __restrict__ A, const short* __restrict__ B0,
                  const short* __restrict__ B1, const float* __restrict__ bias,
                  short* __restrict__ prow, float* __restrict__ qf32) {
    constexpr int KB = 32, S = 8;
    __shared__ float sC[4][32][68];
    int rowBlk, colHalf;
    if (!xcd_map(blockIdx.x, rowBlk, colHalf)) return;
    const int tid = threadIdx.x, wave = tid >> 6, lane = tid & 63;
    const int lhi = lane >> 4, llo = lane & 15;
    const int rowBase = rowBlk * 256 + wave * 64;
    const int colBase = colHalf * 64;
    const int rowTile = rowBase >> 4, colTile = colBase >> 4;

    f32x4 accp[4][4], accq[4][4];
    #pragma unroll
    for (int i = 0; i < 4; ++i)
        #pragma unroll
        for (int j = 0; j < 4; ++j)
            #pragma unroll
            for (int r = 0; r < 4; ++r) { accp[i][j][r] = 0.f; accq[i][j][r] = 0.f; }

    bf16x8 a[4];
    #pragma unroll
    for (int i = 0; i < 4; ++i)
        a[i] = *(const bf16x8*)(A + ((size_t)(rowTile + i) * KB + lhi) * 128 + (size_t)llo * 8);

    #pragma unroll
    for (int s = 0; s < S; ++s) {
        const int kb = s * 4 + lhi;
        bf16x8 b0[4], b1[4];
        #pragma unroll
        for (int j = 0; j < 4; ++j) {
            b0[j] = *(const bf16x8*)(B0 + ((size_t)(colTile + j) * KB + kb) * 128 + (size_t)llo * 8);
            b1[j] = *(const bf16x8*)(B1 + ((size_t)(colTile + j) * KB + kb) * 128 + (size_t)llo * 8);
        }
        bf16x8 an[4];
        if (s + 1 < S) {
            const int kb1 = (s + 1) * 4 + lhi;
            #pragma unroll
            for (int i = 0; i < 4; ++i)
                an[i] = *(const bf16x8*)(A + ((size_t)(rowTile + i) * KB + kb1) * 128 + (size_t)llo * 8);
        }
        #pragma unroll
        for (int i = 0; i < 4; ++i)
            #pragma unroll
            for (int j = 0; j < 4; ++j) {
                accp[i][j] = __builtin_amdgcn_mfma_f32_16x16x32_bf16(a[i], b0[j], accp[i][j], 0, 0, 0);
                accq[i][j] = __builtin_amdgcn_mfma_f32_16x16x32_bf16(a[i], b1[j], accq[i][j], 0, 0, 0);
            }
        if (s + 1 < S) {
            #pragma unroll
            for (int i = 0; i < 4; ++i) a[i] = an[i];
        }
    }

    // p epilogue: bf16 row-major
    #pragma unroll
    for (int half = 0; half < 2; ++half) {
        #pragma unroll
        for (int i2 = 0; i2 < 2; ++i2) {
            const int i = half * 2 + i2;
            #pragma unroll
            for (int j = 0; j < 4; ++j)
                #pragma unroll
                for (int r = 0; r < 4; ++r)
                    sC[wave][i2 * 16 + lhi * 4 + r][j * 16 + llo] = accp[i][j][r];
        }
        #pragma unroll
        for (int it = 0; it < 4; ++it) {
            const int r = it * 8 + (lane >> 3);
            const int c = (lane & 7) * 8;
            const int grow = rowBase + half * 32 + r;
            if (grow < N_NODES) {
                float4 v0 = *(const float4*)&sC[wave][r][c];
                float4 v1 = *(const float4*)&sC[wave][r][c + 4];
                __align__(16) short sv[8] = {f2bf(v0.x), f2bf(v0.y), f2bf(v0.z), f2bf(v0.w),
                                             f2bf(v1.x), f2bf(v1.y), f2bf(v1.z), f2bf(v1.w)};
                *(int4*)(prow + (size_t)grow * 128 + colBase + c) = *(const int4*)sv;
            }
        }
    }

    // q epilogue: f32 + bias
    #pragma unroll
    for (int j = 0; j < 4; ++j) {
        float bv = bias[colBase + j * 16 + llo];
        #pragma unroll
        for (int i = 0; i < 4; ++i)
            #pragma unroll
            for (int r = 0; r < 4; ++r) accq[i][j][r] += bv;
    }
    #pragma unroll
    for (int half = 0; half < 2; ++half) {
        #pragma unroll
        for (int i2 = 0; i2 < 2; ++i2) {
            const int i = half * 2 + i2;
            #pragma unroll
            for (int j = 0; j < 4; ++j)
                #pragma unroll
                for (int r = 0; r < 4; ++r)
                    sC[wave][i2 * 16 + lhi * 4 + r][j * 16 + llo] = accq[i][j][r];
        }
        #pragma unroll
        for (int it = 0; it < 4; ++it) {
            const int r = it * 8 + (lane >> 3);
            const int c = (lane & 7) * 8;
            const int grow = rowBase + half * 32 + r;
            if (grow < N_NODES) {
                float4 v0 = *(const float4*)&sC[wave][r][c];
                float4 v1 = *(const float4*)&sC[wave][r][c + 4];
                *(float4*)(qf32 + (size_t)grow * 128 + colBase + c) = v0;
                *(float4*)(qf32 + (size_t)grow * 128 + colBase + c + 4) = v1;
            }
        }
    }
}

extern "C" void kernel_launch(void* const* d_in, const int* in_sizes, int n_in,
                              void* d_out, int out_size, void* d_ws, size_t ws_size,
                              hipStream_t stream) {
    const float* x   = (const float*)d_in[0];
    const int*   ei  = (const int*)d_in[1];
    const float* Wl1 = (const float*)d_in[2];
    const float* b1  = (const float*)d_in[3];
    const float* Wr1 = (const float*)d_in[4];
    const float* Wl2 = (const float*)d_in[5];
    const float* b2  = (const float*)d_in[6];
    const float* Wr2 = (const float*)d_in[7];
    const int E = in_sizes[1] / 2;
    const int* src = ei;
    const int* dst = ei + E;

    // workspace layout
    short* h_pack = (short*)d_ws;                    // NPAD*256
    short* agg1p  = h_pack + (size_t)NPAD * 256;     // NPAD*128
    unsigned char* x_fp8 = (unsigned char*)(agg1p + (size_t)NPAD * 128); // NPAD*128 bytes (in old x_row slot)
    short* x_pack = (short*)(x_fp8 + (size_t)NPAD * 256); // NPAD*128 (slot size kept = NPAD*128 shorts)
    short* p_row  = x_pack + (size_t)NPAD * 128;     // NPAD*128
    short* wl1p   = p_row  + (size_t)NPAD * 128;     // 32768
    short* wr1p   = wl1p + 32768;
    short* wl2p   = wr1p + 32768;
    short* wr2p   = wl2p + 32768;
    int* bucket_cnt    = (int*)(wr2p + 32768);       // NBLK+1
    int* bucket_base   = bucket_cnt + NBLK + 1;      // NBLK+1
    int* bucket_cursor = bucket_base + NBLK + 1;     // NBLK+1
    int* offsets       = bucket_cursor + NBLK + 1;   // N+1
    unsigned int* bin  = (unsigned int*)(offsets + N_NODES + 1); // E
    int* sorted        = (int*)(bin + E);            // E

    const int nbin = (E + 4095) / 4096;

    // CSR build (binned two-pass counting sort)
    hipMemsetAsync(bucket_cnt, 0, (NBLK + 1) * sizeof(int), stream);
    cbuck_kernel<<<nbin, 256, 0, stream>>>(dst, bucket_cnt, E);
    scan391_kernel<<<1, 512, 0, stream>>>(bucket_cnt, bucket_base, bucket_cursor, offsets);
    bin_kernel<<<nbin, 256, 0, stream>>>(src, dst, bucket_cursor, bin, E);
    place_kernel<<<NBLK, 256, 0, stream>>>(bin, bucket_base, offsets, sorted);

    // fused bf16/fp8 conversions / packing (x + all 4 weights)
    prep_kernel<<<(N_NODES * 16 + 4 * 32768 + 255) / 256, 256, 0, stream>>>(
        x, x_fp8, x_pack, Wl1, Wr1, Wl2, Wr2, wl1p, wr1p, wl2p, wr2p);

    // layer 1: agg(x) [fp8 gather, deg-gated bf16 fallback] -> h = relu([mean,x]@[Wl1;Wr1] + b1)
    aggregate_x_kernel<<<(N_NODES + 3) / 4, 256, 0, stream>>>(x_fp8, x_pack, offsets, sorted, agg1p);
    gemm1_kernel<<<GEMM_GRID, 256, 0, stream>>>(agg1p, x_pack, wl1p, wr1p, b1, h_pack);

    // layer 2 (commuted): p = h@Wl2; q = h@Wr2 + b2 -> d_out; d_out += mean(p)
    gemm2_kernel<<<GEMM_GRID, 256, 0, stream>>>(h_pack, wl2p, wr2p, b2, p_row, (float*)d_out);
    aggregate_p_kernel<<<(N_NODES + 3) / 4, 256, 0, stream>>>(p_row, offsets, sorted, (float*)d_out);
}